// Round 11
// baseline (183.041 us; speedup 1.0000x reference)
//
#include <hip/hip_runtime.h>
#include <math.h>

#define S 2048
#define H 16
#define D 64
#define V 1024

typedef float f32x4 __attribute__((ext_vector_type(4)));
typedef __bf16 bf16x8 __attribute__((ext_vector_type(8)));
typedef unsigned short u16;

#define GLOBAL_AS __attribute__((address_space(1)))
#define LDS_AS __attribute__((address_space(3)))

__device__ __forceinline__ u16 f2bf(float x) {
    unsigned u = __float_as_uint(x);
    u = u + 0x7FFFu + ((u >> 16) & 1u);   // RNE
    return (u16)(u >> 16);
}
__device__ __forceinline__ float bf2f(u16 b) {
    return __uint_as_float(((unsigned)b) << 16);
}

#if __has_builtin(__builtin_amdgcn_global_load_lds)
#define HAS_ASYNC 1
#endif

// async 16B/lane global->LDS; lds base wave-uniform, HW scatters lane*16.
__device__ __forceinline__ void async_ld16(const u16* g, u16* ldsu, int lane) {
#ifdef HAS_ASYNC
    auto gp = reinterpret_cast<GLOBAL_AS void*>(reinterpret_cast<uintptr_t>(g));
    auto lp = reinterpret_cast<LDS_AS void*>(reinterpret_cast<uintptr_t>(ldsu));
    __builtin_amdgcn_global_load_lds(gp, lp, 16, 0, 0);
#else
    *(uint4*)((char*)ldsu + lane * 16) = *(const uint4*)g;
#endif
}

// ---------------- prep: f32 -> bf16, 5 arrays, float4-vectorized ------------
__global__ __launch_bounds__(256) void prep5(
    const float* __restrict__ a0, u16* __restrict__ b0, int n0,
    const float* __restrict__ a1, u16* __restrict__ b1, int n1,
    const float* __restrict__ a2, u16* __restrict__ b2, int n2,
    const float* __restrict__ a3, u16* __restrict__ b3, int n3,
    const float* __restrict__ a4, u16* __restrict__ b4, int n4)
{
    const int tot = n0 + n1 + n2 + n3 + n4;   // float4 units
    for (int i = blockIdx.x * 256 + threadIdx.x; i < tot; i += gridDim.x * 256) {
        const float* s; u16* d; int j = i;
        if (j < n0) { s = a0; d = b0; }
        else if ((j -= n0) < n1) { s = a1; d = b1; }
        else if ((j -= n1) < n2) { s = a2; d = b2; }
        else if ((j -= n2) < n3) { s = a3; d = b3; }
        else { j -= n3; s = a4; d = b4; }
        float4 f = ((const float4*)s)[j];
        ((ushort4*)d)[j] = make_ushort4(f2bf(f.x), f2bf(f.y), f2bf(f.z), f2bf(f.w));
    }
}

// ---------------- projection GEMM: 128x128, BK=64, 2-phase dbuf (r8-exact) -
// r9 closed the tile branch: 128x64+dbuf REGRESSED (non-attn 115.9->118.9) —
// with the 2-phase pipeline hiding latency, per-block arithmetic intensity
// (MFMA per barrier, B-reuse) dominates, not blocks/CU. This 128x128 config
// is the measured best (r8: non-attn 115.9us).
__global__ __launch_bounds__(256) void gemm_proj(
    const u16* __restrict__ x_h, const u16* __restrict__ rel_h,
    const u16* __restrict__ Wq_h, const u16* __restrict__ Wpos_h,
    u16* __restrict__ qk_h, u16* __restrict__ Vt_g, u16* __restrict__ P_h)
{
    __shared__ u16 A_s[2][128 * 64];
    __shared__ u16 B_s[2][128 * 64];

    const int bid = blockIdx.x;
    const bool g1 = bid < 384;
    const int m0 = (g1 ? (bid / 24) : ((bid - 384) / 8)) * 128;
    const int n0 = (g1 ? (bid % 24) : ((bid - 384) % 8)) * 128;
    const u16* Ag = g1 ? x_h : rel_h;
    const u16* Bg = g1 ? Wq_h : Wpos_h;

    const int tid = threadIdx.x;
    const int lane = tid & 63;
    const int w = tid >> 6;
    const int wm = (w & 1) * 64, wn = (w >> 1) * 64;
    const int fr = lane & 15;
    const int fq = lane >> 4;
    const int sr = lane >> 3;                   // 0..7 row within 8-row group
    const int scl = ((lane & 7) ^ sr) * 8;      // inverse-swizzled source col (u16)

    auto stage = [&](int k0, int b) {
#pragma unroll
        for (int i = 0; i < 4; ++i) {
            const int r0 = w * 32 + i * 8;
            async_ld16(Ag + (size_t)(m0 + r0 + sr) * 1024 + k0 + scl, A_s[b] + r0 * 64, lane);
            async_ld16(Bg + (size_t)(n0 + r0 + sr) * 1024 + k0 + scl, B_s[b] + r0 * 64, lane);
        }
    };

    f32x4 acc[4][4] = {};

    stage(0, 0);
    for (int kt = 0; kt < 16; ++kt) {
        __syncthreads();   // drains vmcnt(0): loads(kt) done; buf^1 WAR-safe
        if (kt + 1 < 16) stage((kt + 1) * 64, (kt + 1) & 1);
        const u16* As = A_s[kt & 1];
        const u16* Bs = B_s[kt & 1];
#pragma unroll
        for (int c = 0; c < 2; ++c) {
            // logical slot c*4+fq; phys slot = logical ^ (row&7), row&7 == fr&7
            const int ps = ((c * 4 + fq) ^ (fr & 7)) * 8;
            bf16x8 a[4], b[4];
#pragma unroll
            for (int t = 0; t < 4; ++t) {
                a[t] = *(const bf16x8*)&As[(wm + t * 16 + fr) * 64 + ps];
                b[t] = *(const bf16x8*)&Bs[(wn + t * 16 + fr) * 64 + ps];
            }
#pragma unroll
            for (int mi = 0; mi < 4; ++mi)
#pragma unroll
                for (int ni = 0; ni < 4; ++ni)
                    acc[mi][ni] = __builtin_amdgcn_mfma_f32_16x16x32_bf16(
                        a[mi], b[ni], acc[mi][ni], 0, 0, 0);
        }
    }

    const int er = fq * 4;
    if (g1 && n0 >= 2048) {
#pragma unroll
        for (int mi = 0; mi < 4; ++mi)
#pragma unroll
            for (int ni = 0; ni < 4; ++ni) {
                const int col = n0 - 2048 + wn + ni * 16 + fr;
                const int mrow = m0 + wm + mi * 16 + er;
                *(ushort4*)&Vt_g[(size_t)col * 2048 + mrow] = make_ushort4(
                    f2bf(acc[mi][ni][0]), f2bf(acc[mi][ni][1]),
                    f2bf(acc[mi][ni][2]), f2bf(acc[mi][ni][3]));
            }
    } else {
        u16* Cb = g1 ? qk_h : P_h;
        const int ldc = g1 ? 2048 : 1024;
#pragma unroll
        for (int mi = 0; mi < 4; ++mi)
#pragma unroll
            for (int ni = 0; ni < 4; ++ni)
#pragma unroll
                for (int g = 0; g < 4; ++g)
                    Cb[(size_t)(m0 + wm + mi * 16 + er + g) * ldc + n0 + wn + ni * 16 + fr] =
                        f2bf(acc[mi][ni][g]);
    }
}

// ---------------- MFMA flash attention: r10 + p_s XOR swizzle --------------
// SQ_LDS_BANK_CONFLICT has been flat at 3.78M all session = 448 cy/block-iter
// (~10% of kernel time). Bank math: the 16 scalar u16 p_s writes/thread/iter
// hit bank (16fq+4g+8nt+fr/2)%32 -> fq0/fq2 and fq1/fq3 collide = 4-way.
// Padding can't fix it (16B alignment forces stride = 4/8/12 mod 32 dwords).
// T2 XOR swizzle: store logical col at col ^ 16*((row>>2)&3).
//   write side: (row>>2)&3 == fq  -> col' = (nt^fq)*16 + fr; banks become a
//     perfect 32-bank tiling (G02 at {s,s+16}, G13 at {s+8,s+24}), 2 u16
//     lanes/dword = free.
//   read side (PV A-frag): (row>>2)&3 == fr>>2 -> kk' = kk ^ 16*(fr>>2);
//     enumerated: exactly 8 accesses/bank (the 1KB minimum). Both sides
//     wave-private, consistent.
__global__ __launch_bounds__(256, 3) void attn_mfma(
    const u16* __restrict__ qk_h, const u16* __restrict__ Vt_g,
    const u16* __restrict__ P_h,
    const float* __restrict__ u_vec, const float* __restrict__ v_vec,
    u16* __restrict__ O_h)
{
    const int h = blockIdx.y;
    const int tile = ((blockIdx.y >> 3) & 1) ? blockIdx.x : (gridDim.x - 1 - blockIdx.x);
    const int i0 = tile * 64;
    const int tid = threadIdx.x;
    const int lane = tid & 63;
    const int w = tid >> 6;
    const int fr = lane & 15;
    const int fq = lane >> 4;

    __shared__ u16 K_s[64 * 72];      // B [n=j][k=d]
    __shared__ u16 Vt_s[64 * 72];     // B [n=d][k=j]
    __shared__ u16 P_s[2][64 * 72];   // ping-pong window halves
    __shared__ u16 p_s[64 * 72];      // p, wave-private row bands (XOR-swz)

    // ---- q fragments in registers ----
    bf16x8 qu[2], qv[2];
    {
        const int row = i0 + w * 16 + fr;
        const int base = h * 64 + fq * 8;
#pragma unroll
        for (int c = 0; c < 2; ++c) {
            bf16x8 q8 = *(const bf16x8*)(qk_h + (size_t)row * 2048 + base + c * 32);
            float4 u0 = *(const float4*)(u_vec + base + c * 32);
            float4 u1 = *(const float4*)(u_vec + base + c * 32 + 4);
            float4 v0 = *(const float4*)(v_vec + base + c * 32);
            float4 v1 = *(const float4*)(v_vec + base + c * 32 + 4);
            const float uf[8] = {u0.x, u0.y, u0.z, u0.w, u1.x, u1.y, u1.z, u1.w};
            const float vf[8] = {v0.x, v0.y, v0.z, v0.w, v1.x, v1.y, v1.z, v1.w};
#pragma unroll
            for (int j = 0; j < 8; ++j) {
                const float qf = (float)q8[j];
                qu[c][j] = (__bf16)(qf + uf[j]);
                qv[c][j] = (__bf16)(qf + vf[j]);
            }
        }
    }

    const int rKV = tid >> 2;
    const int cKV = (tid & 3) * 16;
    const int rP = tid >> 2;          // 0..63: new-row index for P staging
    const int cP = (tid & 3) * 16;    // u16 col {0,16,32,48}, pairs at +8

    uint4 pfK0, pfK1, pfV0, pfV1, pfP0, pfP1;
    auto load_pf = [&](int j0) {
        const u16* kg = qk_h + (size_t)(j0 + rKV) * 2048 + 1024 + h * 64 + cKV;
        pfK0 = *(const uint4*)kg;
        pfK1 = *(const uint4*)(kg + 8);
        const u16* vg = Vt_g + (size_t)(h * 64 + rKV) * 2048 + j0 + cKV;
        pfV0 = *(const uint4*)vg;
        pfV1 = *(const uint4*)(vg + 8);
        // upper half of window(j0): logical rows [S+j0-i0, S+j0-i0+64)
        int prow = S + j0 - i0 + rP;
        if (prow > S - 1) prow = S - 1;   // clamped rows only reach masked cells
        const u16* pg = P_h + (size_t)prow * 1024 + h * 64 + cP;
        pfP0 = *(const uint4*)pg;
        pfP1 = *(const uint4*)(pg + 8);
    };

    // ---- prologue: lower half of window(0), rows [S-i0-64, S-i0) -> P_s[0]
    {
        const int prow = S - i0 - 64 + rP;   // always in [0, S)
        const u16* pg = P_h + (size_t)prow * 1024 + h * 64 + cP;
        *(uint4*)&P_s[0][rP * 72 + cP] = *(const uint4*)pg;
        *(uint4*)&P_s[0][rP * 72 + cP + 8] = *(const uint4*)(pg + 8);
    }

    u16* Pcur = P_s[0];   // holds lower half (window rows 0..63)
    u16* Pnxt = P_s[1];   // receives upper half (window rows 64..127)

    f32x4 O[4] = {};
    float l[4] = {};

    const int tbase = 3 - w;          // wave-uniform QP tile offset
    const int bsh = 15 - fq * 4;      // b for g=0; b_g = bsh - g

    load_pf(0);

    for (int j0 = 0; j0 <= i0; j0 += 64) {
        __syncthreads();   // (1) prior iter's cross-wave LDS reads done
        *(uint4*)&K_s[rKV * 72 + cKV] = pfK0;
        *(uint4*)&K_s[rKV * 72 + cKV + 8] = pfK1;
        *(uint4*)&Vt_s[rKV * 72 + cKV] = pfV0;
        *(uint4*)&Vt_s[rKV * 72 + cKV + 8] = pfV1;
        *(uint4*)&Pnxt[rP * 72 + cP] = pfP0;
        *(uint4*)&Pnxt[rP * 72 + cP + 8] = pfP1;
        __syncthreads();   // (2) staging visible to all waves
        if (j0 + 64 <= i0) load_pf(j0 + 64);   // AFTER barrier: overlaps compute

        // ---- QK (4 tiles) + QP (5 tiles, ping-pong halves) MFMA ----
        f32x4 accQK[4] = {};
        f32x4 accQP[5] = {};
#pragma unroll
        for (int c = 0; c < 2; ++c) {
            const int kk = c * 32 + fq * 8;
#pragma unroll
            for (int nt = 0; nt < 4; ++nt) {
                bf16x8 b = *(const bf16x8*)&K_s[(nt * 16 + fr) * 72 + kk];
                accQK[nt] = __builtin_amdgcn_mfma_f32_16x16x32_bf16(qu[c], b, accQK[nt], 0, 0, 0);
            }
#pragma unroll
            for (int t = 0; t < 5; ++t) {
                const int s = tbase + t;                 // 0..7, wave-uniform
                const u16* Pb = (s < 4) ? Pcur : Pnxt;   // uniform select
                bf16x8 b = *(const bf16x8*)&Pb[((s & 3) * 16 + fr) * 72 + kk];
                accQP[t] = __builtin_amdgcn_mfma_f32_16x16x32_bf16(qv[c], b, accQP[t], 0, 0, 0);
            }
        }

        // ---- shift via single shuffle (source-side tile select, r2-exact) --
        float p[4][4];
#pragma unroll
        for (int nt = 0; nt < 4; ++nt)
#pragma unroll
            for (int g = 0; g < 4; ++g) {
                const int b = bsh - g;                 // in [0,15]
                const int srcLane = (fq << 4) | ((fr + b) & 15);
                // exactly one puller per source lane; source selects the tile
                // its puller needs: own fr >= b -> puller took no wrap -> lo
                const float sv = (fr >= b) ? accQP[nt][g] : accQP[nt + 1][g];
                const float qp = __shfl(sv, srcLane, 64);
                const int rr = w * 16 + fq * 4 + g;
                const int j = nt * 16 + fr;
                const float s = (accQK[nt][g] + qp) * 0.125f;
                const float e = ((j0 + j) <= (i0 + rr)) ? __expf(s) : 0.f;
                p[nt][g] = e;
                l[g] += e;
            }
        // p_s write, XOR-swizzled col: (row>>2)&3 == fq here -> col' = (nt^fq)*16+fr
#pragma unroll
        for (int nt = 0; nt < 4; ++nt)
#pragma unroll
            for (int g = 0; g < 4; ++g)
                p_s[(w * 16 + fq * 4 + g) * 72 + ((nt ^ fq) * 16 + fr)] = f2bf(p[nt][g]);
        // no barrier: PV A-read below stays in the wave's band

        // ---- PV MFMA (A-read de-swizzles: kk' = kk ^ 16*(fr>>2)) ----
#pragma unroll
        for (int c = 0; c < 2; ++c) {
            const int kk = c * 32 + fq * 8;
            const int kks = kk ^ ((fr >> 2) * 16);
            bf16x8 a = *(const bf16x8*)&p_s[(w * 16 + fr) * 72 + kks];
#pragma unroll
            for (int nt = 0; nt < 4; ++nt) {
                bf16x8 b = *(const bf16x8*)&Vt_s[(nt * 16 + fr) * 72 + kk];
                O[nt] = __builtin_amdgcn_mfma_f32_16x16x32_bf16(a, b, O[nt], 0, 0, 0);
            }
        }

        // window advances 64 rows: this iter's upper half = next's lower
        u16* tmp = Pcur; Pcur = Pnxt; Pnxt = tmp;
    }

    // ---- reduce l across the 16 fr-lanes (once) ----
#pragma unroll
    for (int g = 0; g < 4; ++g)
#pragma unroll
        for (int off = 1; off < 16; off <<= 1)
            l[g] += __shfl_xor(l[g], off, 64);

    // ---- epilogue: bf16 out ----
#pragma unroll
    for (int nt = 0; nt < 4; ++nt)
#pragma unroll
        for (int g = 0; g < 4; ++g) {
            const int rr = w * 16 + fq * 4 + g;
            O_h[(size_t)(i0 + rr) * 1024 + h * 64 + nt * 16 + fr] = f2bf(O[nt][g] / l[g]);
        }
}

// ---------------- final GEMM: out = O @ Wout^T, 64x64, 2-phase dbuf --------
__global__ __launch_bounds__(256) void gemm_out(
    const u16* __restrict__ O_g, const u16* __restrict__ Wout_h,
    float* __restrict__ C)
{
    __shared__ u16 A_s[2][64 * 32];
    __shared__ u16 B_s[2][64 * 32];

    const int tid = threadIdx.x;
    const int lane = tid & 63;
    const int w = tid >> 6;
    const int m0 = blockIdx.y * 64, n0 = blockIdx.x * 64;
    const int wm = (w & 1) * 32, wn = (w >> 1) * 32;
    const int fr = lane & 15;
    const int fq = lane >> 4;
    const int lr = lane >> 2, lc = (lane & 3) * 8;

    auto stage = [&](int k0, int bi) {
        async_ld16(O_g + (size_t)(m0 + w * 16 + lr) * 1024 + k0 + lc,
                   A_s[bi] + w * 16 * 32, lane);
        async_ld16(Wout_h + (size_t)(n0 + w * 16 + lr) * 1024 + k0 + lc,
                   B_s[bi] + w * 16 * 32, lane);
    };

    f32x4 acc[2][2] = {};

    stage(0, 0);
    for (int kt = 0; kt < 32; ++kt) {
        __syncthreads();   // drains loads(kt); buf^1 WAR-safe
        if (kt + 1 < 32) stage((kt + 1) * 32, (kt + 1) & 1);
        const u16* As = A_s[kt & 1];
        const u16* Bs = B_s[kt & 1];

        bf16x8 a[2], b[2];
#pragma unroll
        for (int t = 0; t < 2; ++t) {
            a[t] = *(const bf16x8*)&As[(wm + t * 16 + fr) * 32 + fq * 8];
            b[t] = *(const bf16x8*)&Bs[(wn + t * 16 + fr) * 32 + fq * 8];
        }
#pragma unroll
        for (int mi = 0; mi < 2; ++mi)
#pragma unroll
            for (int ni = 0; ni < 2; ++ni)
                acc[mi][ni] = __builtin_amdgcn_mfma_f32_16x16x32_bf16(
                    a[mi], b[ni], acc[mi][ni], 0, 0, 0);
    }

    const int er = fq * 4;
#pragma unroll
    for (int mi = 0; mi < 2; ++mi)
#pragma unroll
        for (int ni = 0; ni < 2; ++ni)
#pragma unroll
            for (int g = 0; g < 4; ++g)
                C[(size_t)(m0 + wm + mi * 16 + er + g) * 1024 + n0 + wn + ni * 16 + fr] =
                    acc[mi][ni][g];
}

extern "C" void kernel_launch(void* const* d_in, const int* in_sizes, int n_in,
                              void* d_out, int out_size, void* d_ws, size_t ws_size,
                              hipStream_t stream) {
    const float* x     = (const float*)d_in[0];
    const float* W_qkv = (const float*)d_in[1];
    const float* W_out = (const float*)d_in[2];
    const float* W_pos = (const float*)d_in[3];
    const float* u_vec = (const float*)d_in[4];
    const float* v_vec = (const float*)d_in[5];
    const float* rel   = (const float*)d_in[6];
    float* out = (float*)d_out;

    char* ws = (char*)d_ws;
    u16* x_h    = (u16*)(ws);                 // [2048][1024]
    u16* rel_h  = (u16*)(ws + 4194304);       // [2048][1024]
    u16* Wq_h   = (u16*)(ws + 8388608);       // [3072][1024]
    u16* Wpos_h = (u16*)(ws + 14680064);      // [1024][1024]
    u16* Wout_h = (u16*)(ws + 16777216);      // [1024][1024]
    u16* qk_h   = (u16*)(ws + 18874368);      // [2048][2048] (q | k)
    u16* Vt_g   = (u16*)(ws + 27262976);      // [1024][2048]
    u16* P_h    = (u16*)(ws + 31457280);      // [2048][1024]
    u16* O_h    = (u16*)(ws + 35651584);      // [2048][1024]

    prep5<<<dim3(2048), dim3(256), 0, stream>>>(
        x, x_h, 2048 * 1024 / 4,
        rel, rel_h, 2048 * 1024 / 4,
        W_qkv, Wq_h, 3072 * 1024 / 4,
        W_pos, Wpos_h, 1024 * 1024 / 4,
        W_out, Wout_h, 1024 * 1024 / 4);

    gemm_proj<<<dim3(512), dim3(256), 0, stream>>>(
        x_h, rel_h, Wq_h, Wpos_h, qk_h, Vt_g, P_h);

    attn_mfma<<<dim3(32, 16), dim3(256), 0, stream>>>(
        qk_h, Vt_g, P_h, u_vec, v_vec, O_h);

    gemm_out<<<dim3(16, 32), dim3(256), 0, stream>>>(O_h, Wout_h, out);
}

// Round 12
// 180.866 us; speedup vs baseline: 1.0120x; 1.0120x over previous
//
#include <hip/hip_runtime.h>
#include <math.h>

#define S 2048
#define H 16
#define D 64
#define V 1024

typedef float f32x4 __attribute__((ext_vector_type(4)));
typedef __bf16 bf16x8 __attribute__((ext_vector_type(8)));
typedef unsigned short u16;

#define GLOBAL_AS __attribute__((address_space(1)))
#define LDS_AS __attribute__((address_space(3)))

__device__ __forceinline__ u16 f2bf(float x) {
    unsigned u = __float_as_uint(x);
    u = u + 0x7FFFu + ((u >> 16) & 1u);   // RNE
    return (u16)(u >> 16);
}
__device__ __forceinline__ float bf2f(u16 b) {
    return __uint_as_float(((unsigned)b) << 16);
}

#if __has_builtin(__builtin_amdgcn_global_load_lds)
#define HAS_ASYNC 1
#endif

// async 16B/lane global->LDS; lds base wave-uniform, HW scatters lane*16.
__device__ __forceinline__ void async_ld16(const u16* g, u16* ldsu, int lane) {
#ifdef HAS_ASYNC
    auto gp = reinterpret_cast<GLOBAL_AS void*>(reinterpret_cast<uintptr_t>(g));
    auto lp = reinterpret_cast<LDS_AS void*>(reinterpret_cast<uintptr_t>(ldsu));
    __builtin_amdgcn_global_load_lds(gp, lp, 16, 0, 0);
#else
    *(uint4*)((char*)ldsu + lane * 16) = *(const uint4*)g;
#endif
}

// ---------------- prep: f32 -> bf16, 5 arrays, float4-vectorized ------------
__global__ __launch_bounds__(256) void prep5(
    const float* __restrict__ a0, u16* __restrict__ b0, int n0,
    const float* __restrict__ a1, u16* __restrict__ b1, int n1,
    const float* __restrict__ a2, u16* __restrict__ b2, int n2,
    const float* __restrict__ a3, u16* __restrict__ b3, int n3,
    const float* __restrict__ a4, u16* __restrict__ b4, int n4)
{
    const int tot = n0 + n1 + n2 + n3 + n4;   // float4 units
    for (int i = blockIdx.x * 256 + threadIdx.x; i < tot; i += gridDim.x * 256) {
        const float* s; u16* d; int j = i;
        if (j < n0) { s = a0; d = b0; }
        else if ((j -= n0) < n1) { s = a1; d = b1; }
        else if ((j -= n1) < n2) { s = a2; d = b2; }
        else if ((j -= n2) < n3) { s = a3; d = b3; }
        else { j -= n3; s = a4; d = b4; }
        float4 f = ((const float4*)s)[j];
        ((ushort4*)d)[j] = make_ushort4(f2bf(f.x), f2bf(f.y), f2bf(f.z), f2bf(f.w));
    }
}

// ---------------- projection GEMM: 128x128, BK=64, 2-phase dbuf (r8-exact) -
__global__ __launch_bounds__(256) void gemm_proj(
    const u16* __restrict__ x_h, const u16* __restrict__ rel_h,
    const u16* __restrict__ Wq_h, const u16* __restrict__ Wpos_h,
    u16* __restrict__ qk_h, u16* __restrict__ Vt_g, u16* __restrict__ P_h)
{
    __shared__ u16 A_s[2][128 * 64];
    __shared__ u16 B_s[2][128 * 64];

    const int bid = blockIdx.x;
    const bool g1 = bid < 384;
    const int m0 = (g1 ? (bid / 24) : ((bid - 384) / 8)) * 128;
    const int n0 = (g1 ? (bid % 24) : ((bid - 384) % 8)) * 128;
    const u16* Ag = g1 ? x_h : rel_h;
    const u16* Bg = g1 ? Wq_h : Wpos_h;

    const int tid = threadIdx.x;
    const int lane = tid & 63;
    const int w = tid >> 6;
    const int wm = (w & 1) * 64, wn = (w >> 1) * 64;
    const int fr = lane & 15;
    const int fq = lane >> 4;
    const int sr = lane >> 3;                   // 0..7 row within 8-row group
    const int scl = ((lane & 7) ^ sr) * 8;      // inverse-swizzled source col (u16)

    auto stage = [&](int k0, int b) {
#pragma unroll
        for (int i = 0; i < 4; ++i) {
            const int r0 = w * 32 + i * 8;
            async_ld16(Ag + (size_t)(m0 + r0 + sr) * 1024 + k0 + scl, A_s[b] + r0 * 64, lane);
            async_ld16(Bg + (size_t)(n0 + r0 + sr) * 1024 + k0 + scl, B_s[b] + r0 * 64, lane);
        }
    };

    f32x4 acc[4][4] = {};

    stage(0, 0);
    for (int kt = 0; kt < 16; ++kt) {
        __syncthreads();   // drains vmcnt(0): loads(kt) done; buf^1 WAR-safe
        if (kt + 1 < 16) stage((kt + 1) * 64, (kt + 1) & 1);
        const u16* As = A_s[kt & 1];
        const u16* Bs = B_s[kt & 1];
#pragma unroll
        for (int c = 0; c < 2; ++c) {
            // logical slot c*4+fq; phys slot = logical ^ (row&7), row&7 == fr&7
            const int ps = ((c * 4 + fq) ^ (fr & 7)) * 8;
            bf16x8 a[4], b[4];
#pragma unroll
            for (int t = 0; t < 4; ++t) {
                a[t] = *(const bf16x8*)&As[(wm + t * 16 + fr) * 64 + ps];
                b[t] = *(const bf16x8*)&Bs[(wn + t * 16 + fr) * 64 + ps];
            }
#pragma unroll
            for (int mi = 0; mi < 4; ++mi)
#pragma unroll
                for (int ni = 0; ni < 4; ++ni)
                    acc[mi][ni] = __builtin_amdgcn_mfma_f32_16x16x32_bf16(
                        a[mi], b[ni], acc[mi][ni], 0, 0, 0);
        }
    }

    const int er = fq * 4;
    if (g1 && n0 >= 2048) {
#pragma unroll
        for (int mi = 0; mi < 4; ++mi)
#pragma unroll
            for (int ni = 0; ni < 4; ++ni) {
                const int col = n0 - 2048 + wn + ni * 16 + fr;
                const int mrow = m0 + wm + mi * 16 + er;
                *(ushort4*)&Vt_g[(size_t)col * 2048 + mrow] = make_ushort4(
                    f2bf(acc[mi][ni][0]), f2bf(acc[mi][ni][1]),
                    f2bf(acc[mi][ni][2]), f2bf(acc[mi][ni][3]));
            }
    } else {
        u16* Cb = g1 ? qk_h : P_h;
        const int ldc = g1 ? 2048 : 1024;
#pragma unroll
        for (int mi = 0; mi < 4; ++mi)
#pragma unroll
            for (int ni = 0; ni < 4; ++ni)
#pragma unroll
                for (int g = 0; g < 4; ++g)
                    Cb[(size_t)(m0 + wm + mi * 16 + er + g) * ldc + n0 + wn + ni * 16 + fr] =
                        f2bf(acc[mi][ni][g]);
    }
}

// ---------------- MFMA flash attention: single-barrier pipeline ------------
// r11 falsified the p_s-swizzle bank theory (conflicts UP, dur UP) -> p_s
// reverted to r10 form. New mechanism: all pipes idle (MFMA 8%/VALU 21%/HBM
// 12%) => per-iter serial chain dominates, and the two barriers + staging
// writes pinned between them are its biggest removable piece. Full double-
// buffer K/V + 3-buffer P rotation (chunk c_k -> P_s[k%3]; iter i reads
// c_i,c_{i+1}, writes c_{i+2}) makes every staging write target a buffer
// nobody reads this iteration -> ONE barrier/iter. Writes hide under
// compute. LDS 46->73.7KB is free: grid = 512 blocks = 2 blocks/CU resident
// either way.
__global__ __launch_bounds__(256, 2) void attn_mfma(
    const u16* __restrict__ qk_h, const u16* __restrict__ Vt_g,
    const u16* __restrict__ P_h,
    const float* __restrict__ u_vec, const float* __restrict__ v_vec,
    u16* __restrict__ O_h)
{
    const int h = blockIdx.y;
    const int tile = ((blockIdx.y >> 3) & 1) ? blockIdx.x : (gridDim.x - 1 - blockIdx.x);
    const int i0 = tile * 64;
    const int tid = threadIdx.x;
    const int lane = tid & 63;
    const int w = tid >> 6;
    const int fr = lane & 15;
    const int fq = lane >> 4;

    __shared__ u16 K_s[2][64 * 72];   // double-buffered B [n=j][k=d]
    __shared__ u16 Vt_s[2][64 * 72];  // double-buffered B [n=d][k=j]
    __shared__ u16 P_s[3][64 * 72];   // 3-rotation: chunk c_k -> P_s[k%3]
    __shared__ u16 p_s[64 * 72];      // p, wave-private row bands

    // ---- q fragments in registers ----
    bf16x8 qu[2], qv[2];
    {
        const int row = i0 + w * 16 + fr;
        const int base = h * 64 + fq * 8;
#pragma unroll
        for (int c = 0; c < 2; ++c) {
            bf16x8 q8 = *(const bf16x8*)(qk_h + (size_t)row * 2048 + base + c * 32);
            float4 u0 = *(const float4*)(u_vec + base + c * 32);
            float4 u1 = *(const float4*)(u_vec + base + c * 32 + 4);
            float4 v0 = *(const float4*)(v_vec + base + c * 32);
            float4 v1 = *(const float4*)(v_vec + base + c * 32 + 4);
            const float uf[8] = {u0.x, u0.y, u0.z, u0.w, u1.x, u1.y, u1.z, u1.w};
            const float vf[8] = {v0.x, v0.y, v0.z, v0.w, v1.x, v1.y, v1.z, v1.w};
#pragma unroll
            for (int j = 0; j < 8; ++j) {
                const float qf = (float)q8[j];
                qu[c][j] = (__bf16)(qf + uf[j]);
                qv[c][j] = (__bf16)(qf + vf[j]);
            }
        }
    }

    const int rKV = tid >> 2;
    const int cKV = (tid & 3) * 16;
    const int rP = tid >> 2;          // 0..63: new-row index for P staging
    const int cP = (tid & 3) * 16;    // u16 col {0,16,32,48}, pairs at +8

    uint4 pfK0, pfK1, pfV0, pfV1, pfP0, pfP1;
    // load_pf(j0): K,V of tile j0/64 + P chunk c_{j0/64+1} (rows S+j0-i0+rP)
    auto load_pf = [&](int j0) {
        const u16* kg = qk_h + (size_t)(j0 + rKV) * 2048 + 1024 + h * 64 + cKV;
        pfK0 = *(const uint4*)kg;
        pfK1 = *(const uint4*)(kg + 8);
        const u16* vg = Vt_g + (size_t)(h * 64 + rKV) * 2048 + j0 + cKV;
        pfV0 = *(const uint4*)vg;
        pfV1 = *(const uint4*)(vg + 8);
        int prow = S + j0 - i0 + rP;
        if (prow > S - 1) prow = S - 1;   // clamped rows only reach masked cells
        const u16* pg = P_h + (size_t)prow * 1024 + h * 64 + cP;
        pfP0 = *(const uint4*)pg;
        pfP1 = *(const uint4*)(pg + 8);
    };

    // ---- prologue: stage tile0 fully ----
    {
        // chunk c_0 (lower of window 0): rows [S-i0-64, S-i0) -> P_s[0]
        const int prow = S - i0 - 64 + rP;   // always in [0, S)
        const u16* pg = P_h + (size_t)prow * 1024 + h * 64 + cP;
        *(uint4*)&P_s[0][rP * 72 + cP] = *(const uint4*)pg;
        *(uint4*)&P_s[0][rP * 72 + cP + 8] = *(const uint4*)(pg + 8);
    }
    load_pf(0);                              // tile0 K,V + chunk c_1
    *(uint4*)&K_s[0][rKV * 72 + cKV] = pfK0;
    *(uint4*)&K_s[0][rKV * 72 + cKV + 8] = pfK1;
    *(uint4*)&Vt_s[0][rKV * 72 + cKV] = pfV0;
    *(uint4*)&Vt_s[0][rKV * 72 + cKV + 8] = pfV1;
    *(uint4*)&P_s[1][rP * 72 + cP] = pfP0;
    *(uint4*)&P_s[1][rP * 72 + cP + 8] = pfP1;
    if (i0 >= 64) load_pf(64);               // tile1 K,V + chunk c_2 -> regs

    u16 *Kcur = K_s[0], *Knxt = K_s[1];
    u16 *Vcur = Vt_s[0], *Vnxt = Vt_s[1];
    u16 *Plo = P_s[0], *Phi = P_s[1], *Pwr = P_s[2];

    f32x4 O[4] = {};
    float l[4] = {};

    const int tbase = 3 - w;          // wave-uniform QP tile offset
    const int bsh = 15 - fq * 4;      // b for g=0; b_g = bsh - g

    __syncthreads();   // prologue staging visible (also drains load_pf(64))

    for (int j0 = 0; j0 <= i0; j0 += 64) {
        // ---- write next tile's staged regs into the NON-read buffers ----
        // (iter i-1's reads of these buffers completed before barrier(i-1))
        if (j0 + 64 <= i0) {
            *(uint4*)&Knxt[rKV * 72 + cKV] = pfK0;
            *(uint4*)&Knxt[rKV * 72 + cKV + 8] = pfK1;
            *(uint4*)&Vnxt[rKV * 72 + cKV] = pfV0;
            *(uint4*)&Vnxt[rKV * 72 + cKV + 8] = pfV1;
            *(uint4*)&Pwr[rP * 72 + cP] = pfP0;
            *(uint4*)&Pwr[rP * 72 + cP + 8] = pfP1;
        }
        if (j0 + 128 <= i0) load_pf(j0 + 128);   // drains at this iter's barrier

        // ---- QK (4 tiles) + QP (5 tiles) MFMA ----
        f32x4 accQK[4] = {};
        f32x4 accQP[5] = {};
#pragma unroll
        for (int c = 0; c < 2; ++c) {
            const int kk = c * 32 + fq * 8;
#pragma unroll
            for (int nt = 0; nt < 4; ++nt) {
                bf16x8 b = *(const bf16x8*)&Kcur[(nt * 16 + fr) * 72 + kk];
                accQK[nt] = __builtin_amdgcn_mfma_f32_16x16x32_bf16(qu[c], b, accQK[nt], 0, 0, 0);
            }
#pragma unroll
            for (int t = 0; t < 5; ++t) {
                const int s = tbase + t;               // 0..7, wave-uniform
                const u16* Pb = (s < 4) ? Plo : Phi;   // uniform select
                bf16x8 b = *(const bf16x8*)&Pb[((s & 3) * 16 + fr) * 72 + kk];
                accQP[t] = __builtin_amdgcn_mfma_f32_16x16x32_bf16(qv[c], b, accQP[t], 0, 0, 0);
            }
        }

        // ---- shift via single shuffle (source-side tile select, r2-exact) --
        float p[4][4];
#pragma unroll
        for (int nt = 0; nt < 4; ++nt)
#pragma unroll
            for (int g = 0; g < 4; ++g) {
                const int b = bsh - g;                 // in [0,15]
                const int srcLane = (fq << 4) | ((fr + b) & 15);
                // exactly one puller per source lane; source selects the tile
                // its puller needs: own fr >= b -> puller took no wrap -> lo
                const float sv = (fr >= b) ? accQP[nt][g] : accQP[nt + 1][g];
                const float qp = __shfl(sv, srcLane, 64);
                const int rr = w * 16 + fq * 4 + g;
                const int j = nt * 16 + fr;
                const float s = (accQK[nt][g] + qp) * 0.125f;
                const float e = ((j0 + j) <= (i0 + rr)) ? __expf(s) : 0.f;
                p[nt][g] = e;
                l[g] += e;
            }
#pragma unroll
        for (int nt = 0; nt < 4; ++nt)
#pragma unroll
            for (int g = 0; g < 4; ++g)
                p_s[(w * 16 + fq * 4 + g) * 72 + nt * 16 + fr] = f2bf(p[nt][g]);
        // no barrier: PV A-read below stays in the wave's band

        // ---- PV MFMA ----
#pragma unroll
        for (int c = 0; c < 2; ++c) {
            const int kk = c * 32 + fq * 8;
            bf16x8 a = *(const bf16x8*)&p_s[(w * 16 + fr) * 72 + kk];
#pragma unroll
            for (int nt = 0; nt < 4; ++nt) {
                bf16x8 b = *(const bf16x8*)&Vt_s[0][0];  // placeholder avoided
                b = *(const bf16x8*)&Vcur[(nt * 16 + fr) * 72 + kk];
                O[nt] = __builtin_amdgcn_mfma_f32_16x16x32_bf16(a, b, O[nt], 0, 0, 0);
            }
        }

        __syncthreads();   // the ONE barrier: reads(this iter) & writes done
        // rotate buffers
        { u16* t0 = Kcur; Kcur = Knxt; Knxt = t0; }
        { u16* t1 = Vcur; Vcur = Vnxt; Vnxt = t1; }
        { u16* t2 = Plo; Plo = Phi; Phi = Pwr; Pwr = t2; }
    }

    // ---- reduce l across the 16 fr-lanes (once) ----
#pragma unroll
    for (int g = 0; g < 4; ++g)
#pragma unroll
        for (int off = 1; off < 16; off <<= 1)
            l[g] += __shfl_xor(l[g], off, 64);

    // ---- epilogue: bf16 out ----
#pragma unroll
    for (int nt = 0; nt < 4; ++nt)
#pragma unroll
        for (int g = 0; g < 4; ++g) {
            const int rr = w * 16 + fq * 4 + g;
            O_h[(size_t)(i0 + rr) * 1024 + h * 64 + nt * 16 + fr] = f2bf(O[nt][g] / l[g]);
        }
}

// ---------------- final GEMM: out = O @ Wout^T, 64x64, 2-phase dbuf --------
__global__ __launch_bounds__(256) void gemm_out(
    const u16* __restrict__ O_g, const u16* __restrict__ Wout_h,
    float* __restrict__ C)
{
    __shared__ u16 A_s[2][64 * 32];
    __shared__ u16 B_s[2][64 * 32];

    const int tid = threadIdx.x;
    const int lane = tid & 63;
    const int w = tid >> 6;
    const int m0 = blockIdx.y * 64, n0 = blockIdx.x * 64;
    const int wm = (w & 1) * 32, wn = (w >> 1) * 32;
    const int fr = lane & 15;
    const int fq = lane >> 4;
    const int lr = lane >> 2, lc = (lane & 3) * 8;

    auto stage = [&](int k0, int bi) {
        async_ld16(O_g + (size_t)(m0 + w * 16 + lr) * 1024 + k0 + lc,
                   A_s[bi] + w * 16 * 32, lane);
        async_ld16(Wout_h + (size_t)(n0 + w * 16 + lr) * 1024 + k0 + lc,
                   B_s[bi] + w * 16 * 32, lane);
    };

    f32x4 acc[2][2] = {};

    stage(0, 0);
    for (int kt = 0; kt < 32; ++kt) {
        __syncthreads();   // drains loads(kt); buf^1 WAR-safe
        if (kt + 1 < 32) stage((kt + 1) * 32, (kt + 1) & 1);
        const u16* As = A_s[kt & 1];
        const u16* Bs = B_s[kt & 1];

        bf16x8 a[2], b[2];
#pragma unroll
        for (int t = 0; t < 2; ++t) {
            a[t] = *(const bf16x8*)&As[(wm + t * 16 + fr) * 32 + fq * 8];
            b[t] = *(const bf16x8*)&Bs[(wn + t * 16 + fr) * 32 + fq * 8];
        }
#pragma unroll
        for (int mi = 0; mi < 2; ++mi)
#pragma unroll
            for (int ni = 0; ni < 2; ++ni)
                acc[mi][ni] = __builtin_amdgcn_mfma_f32_16x16x32_bf16(
                    a[mi], b[ni], acc[mi][ni], 0, 0, 0);
    }

    const int er = fq * 4;
#pragma unroll
    for (int mi = 0; mi < 2; ++mi)
#pragma unroll
        for (int ni = 0; ni < 2; ++ni)
#pragma unroll
            for (int g = 0; g < 4; ++g)
                C[(size_t)(m0 + wm + mi * 16 + er + g) * 1024 + n0 + wn + ni * 16 + fr] =
                    acc[mi][ni][g];
}

extern "C" void kernel_launch(void* const* d_in, const int* in_sizes, int n_in,
                              void* d_out, int out_size, void* d_ws, size_t ws_size,
                              hipStream_t stream) {
    const float* x     = (const float*)d_in[0];
    const float* W_qkv = (const float*)d_in[1];
    const float* W_out = (const float*)d_in[2];
    const float* W_pos = (const float*)d_in[3];
    const float* u_vec = (const float*)d_in[4];
    const float* v_vec = (const float*)d_in[5];
    const float* rel   = (const float*)d_in[6];
    float* out = (float*)d_out;

    char* ws = (char*)d_ws;
    u16* x_h    = (u16*)(ws);                 // [2048][1024]
    u16* rel_h  = (u16*)(ws + 4194304);       // [2048][1024]
    u16* Wq_h   = (u16*)(ws + 8388608);       // [3072][1024]
    u16* Wpos_h = (u16*)(ws + 14680064);      // [1024][1024]
    u16* Wout_h = (u16*)(ws + 16777216);      // [1024][1024]
    u16* qk_h   = (u16*)(ws + 18874368);      // [2048][2048] (q | k)
    u16* Vt_g   = (u16*)(ws + 27262976);      // [1024][2048]
    u16* P_h    = (u16*)(ws + 31457280);      // [2048][1024]
    u16* O_h    = (u16*)(ws + 35651584);      // [2048][1024]

    prep5<<<dim3(2048), dim3(256), 0, stream>>>(
        x, x_h, 2048 * 1024 / 4,
        rel, rel_h, 2048 * 1024 / 4,
        W_qkv, Wq_h, 3072 * 1024 / 4,
        W_pos, Wpos_h, 1024 * 1024 / 4,
        W_out, Wout_h, 1024 * 1024 / 4);

    gemm_proj<<<dim3(512), dim3(256), 0, stream>>>(
        x_h, rel_h, Wq_h, Wpos_h, qk_h, Vt_g, P_h);

    attn_mfma<<<dim3(32, 16), dim3(256), 0, stream>>>(
        qk_h, Vt_g, P_h, u_vec, v_vec, O_h);

    gemm_out<<<dim3(16, 32), dim3(256), 0, stream>>>(O_h, Wout_h, out);
}

// Round 13
// 177.119 us; speedup vs baseline: 1.0334x; 1.0212x over previous
//
#include <hip/hip_runtime.h>
#include <math.h>

#define S 2048
#define H 16
#define D 64
#define V 1024

typedef float f32x4 __attribute__((ext_vector_type(4)));
typedef __bf16 bf16x8 __attribute__((ext_vector_type(8)));
typedef unsigned short u16;

#define GLOBAL_AS __attribute__((address_space(1)))
#define LDS_AS __attribute__((address_space(3)))

__device__ __forceinline__ u16 f2bf(float x) {
    unsigned u = __float_as_uint(x);
    u = u + 0x7FFFu + ((u >> 16) & 1u);   // RNE
    return (u16)(u >> 16);
}
__device__ __forceinline__ float bf2f(u16 b) {
    return __uint_as_float(((unsigned)b) << 16);
}

#if __has_builtin(__builtin_amdgcn_global_load_lds)
#define HAS_ASYNC 1
#endif

// async 16B/lane global->LDS; lds base wave-uniform, HW scatters lane*16.
__device__ __forceinline__ void async_ld16(const u16* g, u16* ldsu, int lane) {
#ifdef HAS_ASYNC
    auto gp = reinterpret_cast<GLOBAL_AS void*>(reinterpret_cast<uintptr_t>(g));
    auto lp = reinterpret_cast<LDS_AS void*>(reinterpret_cast<uintptr_t>(ldsu));
    __builtin_amdgcn_global_load_lds(gp, lp, 16, 0, 0);
#else
    *(uint4*)((char*)ldsu + lane * 16) = *(const uint4*)g;
#endif
}

// ---------------- prep: f32 -> bf16, 5 arrays, float4-vectorized ------------
__global__ __launch_bounds__(256) void prep5(
    const float* __restrict__ a0, u16* __restrict__ b0, int n0,
    const float* __restrict__ a1, u16* __restrict__ b1, int n1,
    const float* __restrict__ a2, u16* __restrict__ b2, int n2,
    const float* __restrict__ a3, u16* __restrict__ b3, int n3,
    const float* __restrict__ a4, u16* __restrict__ b4, int n4)
{
    const int tot = n0 + n1 + n2 + n3 + n4;   // float4 units
    for (int i = blockIdx.x * 256 + threadIdx.x; i < tot; i += gridDim.x * 256) {
        const float* s; u16* d; int j = i;
        if (j < n0) { s = a0; d = b0; }
        else if ((j -= n0) < n1) { s = a1; d = b1; }
        else if ((j -= n1) < n2) { s = a2; d = b2; }
        else if ((j -= n2) < n3) { s = a3; d = b3; }
        else { j -= n3; s = a4; d = b4; }
        float4 f = ((const float4*)s)[j];
        ((ushort4*)d)[j] = make_ushort4(f2bf(f.x), f2bf(f.y), f2bf(f.z), f2bf(f.w));
    }
}

// ---------------- projection GEMM: 128x128, BK=64, 2-phase dbuf + T1 -------
// r8 structure (measured best). NEW (T1): XCD-aware bijective block swizzle
// (nwg=512 = 8*64): consecutive bids share a 256KB A-panel (24 bids per
// m-group); default round-robin spreads them over all 8 XCD L2s. Contiguous
// 64-block chunks per XCD -> A-panel re-reads become XCD-local L2 hits.
// Pure work permutation: correctness-neutral.
__global__ __launch_bounds__(256) void gemm_proj(
    const u16* __restrict__ x_h, const u16* __restrict__ rel_h,
    const u16* __restrict__ Wq_h, const u16* __restrict__ Wpos_h,
    u16* __restrict__ qk_h, u16* __restrict__ Vt_g, u16* __restrict__ P_h)
{
    __shared__ u16 A_s[2][128 * 64];
    __shared__ u16 B_s[2][128 * 64];

    const int bid = (blockIdx.x & 7) * 64 + (blockIdx.x >> 3);   // T1 swizzle
    const bool g1 = bid < 384;
    const int m0 = (g1 ? (bid / 24) : ((bid - 384) / 8)) * 128;
    const int n0 = (g1 ? (bid % 24) : ((bid - 384) % 8)) * 128;
    const u16* Ag = g1 ? x_h : rel_h;
    const u16* Bg = g1 ? Wq_h : Wpos_h;

    const int tid = threadIdx.x;
    const int lane = tid & 63;
    const int w = tid >> 6;
    const int wm = (w & 1) * 64, wn = (w >> 1) * 64;
    const int fr = lane & 15;
    const int fq = lane >> 4;
    const int sr = lane >> 3;                   // 0..7 row within 8-row group
    const int scl = ((lane & 7) ^ sr) * 8;      // inverse-swizzled source col (u16)

    auto stage = [&](int k0, int b) {
#pragma unroll
        for (int i = 0; i < 4; ++i) {
            const int r0 = w * 32 + i * 8;
            async_ld16(Ag + (size_t)(m0 + r0 + sr) * 1024 + k0 + scl, A_s[b] + r0 * 64, lane);
            async_ld16(Bg + (size_t)(n0 + r0 + sr) * 1024 + k0 + scl, B_s[b] + r0 * 64, lane);
        }
    };

    f32x4 acc[4][4] = {};

    stage(0, 0);
    for (int kt = 0; kt < 16; ++kt) {
        __syncthreads();   // drains vmcnt(0): loads(kt) done; buf^1 WAR-safe
        if (kt + 1 < 16) stage((kt + 1) * 64, (kt + 1) & 1);
        const u16* As = A_s[kt & 1];
        const u16* Bs = B_s[kt & 1];
#pragma unroll
        for (int c = 0; c < 2; ++c) {
            // logical slot c*4+fq; phys slot = logical ^ (row&7), row&7 == fr&7
            const int ps = ((c * 4 + fq) ^ (fr & 7)) * 8;
            bf16x8 a[4], b[4];
#pragma unroll
            for (int t = 0; t < 4; ++t) {
                a[t] = *(const bf16x8*)&As[(wm + t * 16 + fr) * 64 + ps];
                b[t] = *(const bf16x8*)&Bs[(wn + t * 16 + fr) * 64 + ps];
            }
#pragma unroll
            for (int mi = 0; mi < 4; ++mi)
#pragma unroll
                for (int ni = 0; ni < 4; ++ni)
                    acc[mi][ni] = __builtin_amdgcn_mfma_f32_16x16x32_bf16(
                        a[mi], b[ni], acc[mi][ni], 0, 0, 0);
        }
    }

    const int er = fq * 4;
    if (g1 && n0 >= 2048) {
#pragma unroll
        for (int mi = 0; mi < 4; ++mi)
#pragma unroll
            for (int ni = 0; ni < 4; ++ni) {
                const int col = n0 - 2048 + wn + ni * 16 + fr;
                const int mrow = m0 + wm + mi * 16 + er;
                *(ushort4*)&Vt_g[(size_t)col * 2048 + mrow] = make_ushort4(
                    f2bf(acc[mi][ni][0]), f2bf(acc[mi][ni][1]),
                    f2bf(acc[mi][ni][2]), f2bf(acc[mi][ni][3]));
            }
    } else {
        u16* Cb = g1 ? qk_h : P_h;
        const int ldc = g1 ? 2048 : 1024;
#pragma unroll
        for (int mi = 0; mi < 4; ++mi)
#pragma unroll
            for (int ni = 0; ni < 4; ++ni)
#pragma unroll
                for (int g = 0; g < 4; ++g)
                    Cb[(size_t)(m0 + wm + mi * 16 + er + g) * ldc + n0 + wn + ni * 16 + fr] =
                        f2bf(acc[mi][ni][g]);
    }
}

// ---------------- MFMA flash attention: single-barrier pipeline (r12) ------
// Double-buffered K/V + 3-buffer P rotation -> one barrier/iter; staging
// writes hide under compute. Measured 60.7us (r12).
__global__ __launch_bounds__(256, 2) void attn_mfma(
    const u16* __restrict__ qk_h, const u16* __restrict__ Vt_g,
    const u16* __restrict__ P_h,
    const float* __restrict__ u_vec, const float* __restrict__ v_vec,
    u16* __restrict__ O_h)
{
    const int h = blockIdx.y;
    const int tile = ((blockIdx.y >> 3) & 1) ? blockIdx.x : (gridDim.x - 1 - blockIdx.x);
    const int i0 = tile * 64;
    const int tid = threadIdx.x;
    const int lane = tid & 63;
    const int w = tid >> 6;
    const int fr = lane & 15;
    const int fq = lane >> 4;

    __shared__ u16 K_s[2][64 * 72];   // double-buffered B [n=j][k=d]
    __shared__ u16 Vt_s[2][64 * 72];  // double-buffered B [n=d][k=j]
    __shared__ u16 P_s[3][64 * 72];   // 3-rotation: chunk c_k -> P_s[k%3]
    __shared__ u16 p_s[64 * 72];      // p, wave-private row bands

    // ---- q fragments in registers ----
    bf16x8 qu[2], qv[2];
    {
        const int row = i0 + w * 16 + fr;
        const int base = h * 64 + fq * 8;
#pragma unroll
        for (int c = 0; c < 2; ++c) {
            bf16x8 q8 = *(const bf16x8*)(qk_h + (size_t)row * 2048 + base + c * 32);
            float4 u0 = *(const float4*)(u_vec + base + c * 32);
            float4 u1 = *(const float4*)(u_vec + base + c * 32 + 4);
            float4 v0 = *(const float4*)(v_vec + base + c * 32);
            float4 v1 = *(const float4*)(v_vec + base + c * 32 + 4);
            const float uf[8] = {u0.x, u0.y, u0.z, u0.w, u1.x, u1.y, u1.z, u1.w};
            const float vf[8] = {v0.x, v0.y, v0.z, v0.w, v1.x, v1.y, v1.z, v1.w};
#pragma unroll
            for (int j = 0; j < 8; ++j) {
                const float qf = (float)q8[j];
                qu[c][j] = (__bf16)(qf + uf[j]);
                qv[c][j] = (__bf16)(qf + vf[j]);
            }
        }
    }

    const int rKV = tid >> 2;
    const int cKV = (tid & 3) * 16;
    const int rP = tid >> 2;          // 0..63: new-row index for P staging
    const int cP = (tid & 3) * 16;    // u16 col {0,16,32,48}, pairs at +8

    uint4 pfK0, pfK1, pfV0, pfV1, pfP0, pfP1;
    // load_pf(j0): K,V of tile j0/64 + P chunk c_{j0/64+1} (rows S+j0-i0+rP)
    auto load_pf = [&](int j0) {
        const u16* kg = qk_h + (size_t)(j0 + rKV) * 2048 + 1024 + h * 64 + cKV;
        pfK0 = *(const uint4*)kg;
        pfK1 = *(const uint4*)(kg + 8);
        const u16* vg = Vt_g + (size_t)(h * 64 + rKV) * 2048 + j0 + cKV;
        pfV0 = *(const uint4*)vg;
        pfV1 = *(const uint4*)(vg + 8);
        int prow = S + j0 - i0 + rP;
        if (prow > S - 1) prow = S - 1;   // clamped rows only reach masked cells
        const u16* pg = P_h + (size_t)prow * 1024 + h * 64 + cP;
        pfP0 = *(const uint4*)pg;
        pfP1 = *(const uint4*)(pg + 8);
    };

    // ---- prologue: stage tile0 fully ----
    {
        // chunk c_0 (lower of window 0): rows [S-i0-64, S-i0) -> P_s[0]
        const int prow = S - i0 - 64 + rP;   // always in [0, S)
        const u16* pg = P_h + (size_t)prow * 1024 + h * 64 + cP;
        *(uint4*)&P_s[0][rP * 72 + cP] = *(const uint4*)pg;
        *(uint4*)&P_s[0][rP * 72 + cP + 8] = *(const uint4*)(pg + 8);
    }
    load_pf(0);                              // tile0 K,V + chunk c_1
    *(uint4*)&K_s[0][rKV * 72 + cKV] = pfK0;
    *(uint4*)&K_s[0][rKV * 72 + cKV + 8] = pfK1;
    *(uint4*)&Vt_s[0][rKV * 72 + cKV] = pfV0;
    *(uint4*)&Vt_s[0][rKV * 72 + cKV + 8] = pfV1;
    *(uint4*)&P_s[1][rP * 72 + cP] = pfP0;
    *(uint4*)&P_s[1][rP * 72 + cP + 8] = pfP1;
    if (i0 >= 64) load_pf(64);               // tile1 K,V + chunk c_2 -> regs

    u16 *Kcur = K_s[0], *Knxt = K_s[1];
    u16 *Vcur = Vt_s[0], *Vnxt = Vt_s[1];
    u16 *Plo = P_s[0], *Phi = P_s[1], *Pwr = P_s[2];

    f32x4 O[4] = {};
    float l[4] = {};

    const int tbase = 3 - w;          // wave-uniform QP tile offset
    const int bsh = 15 - fq * 4;      // b for g=0; b_g = bsh - g

    __syncthreads();   // prologue staging visible (also drains load_pf(64))

    for (int j0 = 0; j0 <= i0; j0 += 64) {
        // ---- write next tile's staged regs into the NON-read buffers ----
        // (iter i-1's reads of these buffers completed before barrier(i-1))
        if (j0 + 64 <= i0) {
            *(uint4*)&Knxt[rKV * 72 + cKV] = pfK0;
            *(uint4*)&Knxt[rKV * 72 + cKV + 8] = pfK1;
            *(uint4*)&Vnxt[rKV * 72 + cKV] = pfV0;
            *(uint4*)&Vnxt[rKV * 72 + cKV + 8] = pfV1;
            *(uint4*)&Pwr[rP * 72 + cP] = pfP0;
            *(uint4*)&Pwr[rP * 72 + cP + 8] = pfP1;
        }
        if (j0 + 128 <= i0) load_pf(j0 + 128);   // drains at this iter's barrier

        // ---- QK (4 tiles) + QP (5 tiles) MFMA ----
        f32x4 accQK[4] = {};
        f32x4 accQP[5] = {};
#pragma unroll
        for (int c = 0; c < 2; ++c) {
            const int kk = c * 32 + fq * 8;
#pragma unroll
            for (int nt = 0; nt < 4; ++nt) {
                bf16x8 b = *(const bf16x8*)&Kcur[(nt * 16 + fr) * 72 + kk];
                accQK[nt] = __builtin_amdgcn_mfma_f32_16x16x32_bf16(qu[c], b, accQK[nt], 0, 0, 0);
            }
#pragma unroll
            for (int t = 0; t < 5; ++t) {
                const int s = tbase + t;               // 0..7, wave-uniform
                const u16* Pb = (s < 4) ? Plo : Phi;   // uniform select
                bf16x8 b = *(const bf16x8*)&Pb[((s & 3) * 16 + fr) * 72 + kk];
                accQP[t] = __builtin_amdgcn_mfma_f32_16x16x32_bf16(qv[c], b, accQP[t], 0, 0, 0);
            }
        }

        // ---- shift via single shuffle (source-side tile select, r2-exact) --
        float p[4][4];
#pragma unroll
        for (int nt = 0; nt < 4; ++nt)
#pragma unroll
            for (int g = 0; g < 4; ++g) {
                const int b = bsh - g;                 // in [0,15]
                const int srcLane = (fq << 4) | ((fr + b) & 15);
                // exactly one puller per source lane; source selects the tile
                // its puller needs: own fr >= b -> puller took no wrap -> lo
                const float sv = (fr >= b) ? accQP[nt][g] : accQP[nt + 1][g];
                const float qp = __shfl(sv, srcLane, 64);
                const int rr = w * 16 + fq * 4 + g;
                const int j = nt * 16 + fr;
                const float s = (accQK[nt][g] + qp) * 0.125f;
                const float e = ((j0 + j) <= (i0 + rr)) ? __expf(s) : 0.f;
                p[nt][g] = e;
                l[g] += e;
            }
#pragma unroll
        for (int nt = 0; nt < 4; ++nt)
#pragma unroll
            for (int g = 0; g < 4; ++g)
                p_s[(w * 16 + fq * 4 + g) * 72 + nt * 16 + fr] = f2bf(p[nt][g]);
        // no barrier: PV A-read below stays in the wave's band

        // ---- PV MFMA ----
#pragma unroll
        for (int c = 0; c < 2; ++c) {
            const int kk = c * 32 + fq * 8;
            bf16x8 a = *(const bf16x8*)&p_s[(w * 16 + fr) * 72 + kk];
#pragma unroll
            for (int nt = 0; nt < 4; ++nt) {
                bf16x8 b = *(const bf16x8*)&Vcur[(nt * 16 + fr) * 72 + kk];
                O[nt] = __builtin_amdgcn_mfma_f32_16x16x32_bf16(a, b, O[nt], 0, 0, 0);
            }
        }

        __syncthreads();   // the ONE barrier: reads(this iter) & writes done
        // rotate buffers
        { u16* t0 = Kcur; Kcur = Knxt; Knxt = t0; }
        { u16* t1 = Vcur; Vcur = Vnxt; Vnxt = t1; }
        { u16* t2 = Plo; Plo = Phi; Phi = Pwr; Pwr = t2; }
    }

    // ---- reduce l across the 16 fr-lanes (once) ----
#pragma unroll
    for (int g = 0; g < 4; ++g)
#pragma unroll
        for (int off = 1; off < 16; off <<= 1)
            l[g] += __shfl_xor(l[g], off, 64);

    // ---- epilogue: bf16 out ----
#pragma unroll
    for (int nt = 0; nt < 4; ++nt)
#pragma unroll
        for (int g = 0; g < 4; ++g) {
            const int rr = w * 16 + fq * 4 + g;
            O_h[(size_t)(i0 + rr) * 1024 + h * 64 + nt * 16 + fr] = f2bf(O[nt][g] / l[g]);
        }
}

// ---------------- final GEMM: out = O @ Wout^T, 64x64, 2-phase dbuf + T1 ---
// 1D grid (512 blocks) with the same bijective XCD swizzle; internal
// (m0, n0) decomposition unchanged from the 2D version.
__global__ __launch_bounds__(256) void gemm_out(
    const u16* __restrict__ O_g, const u16* __restrict__ Wout_h,
    float* __restrict__ C)
{
    __shared__ u16 A_s[2][64 * 32];
    __shared__ u16 B_s[2][64 * 32];

    const int lin = (blockIdx.x & 7) * 64 + (blockIdx.x >> 3);   // T1 swizzle
    const int m0 = (lin >> 4) * 64, n0 = (lin & 15) * 64;

    const int tid = threadIdx.x;
    const int lane = tid & 63;
    const int w = tid >> 6;
    const int wm = (w & 1) * 32, wn = (w >> 1) * 32;
    const int fr = lane & 15;
    const int fq = lane >> 4;
    const int lr = lane >> 2, lc = (lane & 3) * 8;

    auto stage = [&](int k0, int bi) {
        async_ld16(O_g + (size_t)(m0 + w * 16 + lr) * 1024 + k0 + lc,
                   A_s[bi] + w * 16 * 32, lane);
        async_ld16(Wout_h + (size_t)(n0 + w * 16 + lr) * 1024 + k0 + lc,
                   B_s[bi] + w * 16 * 32, lane);
    };

    f32x4 acc[2][2] = {};

    stage(0, 0);
    for (int kt = 0; kt < 32; ++kt) {
        __syncthreads();   // drains loads(kt); buf^1 WAR-safe
        if (kt + 1 < 32) stage((kt + 1) * 32, (kt + 1) & 1);
        const u16* As = A_s[kt & 1];
        const u16* Bs = B_s[kt & 1];

        bf16x8 a[2], b[2];
#pragma unroll
        for (int t = 0; t < 2; ++t) {
            a[t] = *(const bf16x8*)&As[(wm + t * 16 + fr) * 32 + fq * 8];
            b[t] = *(const bf16x8*)&Bs[(wn + t * 16 + fr) * 32 + fq * 8];
        }
#pragma unroll
        for (int mi = 0; mi < 2; ++mi)
#pragma unroll
            for (int ni = 0; ni < 2; ++ni)
                acc[mi][ni] = __builtin_amdgcn_mfma_f32_16x16x32_bf16(
                    a[mi], b[ni], acc[mi][ni], 0, 0, 0);
    }

    const int er = fq * 4;
#pragma unroll
    for (int mi = 0; mi < 2; ++mi)
#pragma unroll
        for (int ni = 0; ni < 2; ++ni)
#pragma unroll
            for (int g = 0; g < 4; ++g)
                C[(size_t)(m0 + wm + mi * 16 + er + g) * 1024 + n0 + wn + ni * 16 + fr] =
                    acc[mi][ni][g];
}

extern "C" void kernel_launch(void* const* d_in, const int* in_sizes, int n_in,
                              void* d_out, int out_size, void* d_ws, size_t ws_size,
                              hipStream_t stream) {
    const float* x     = (const float*)d_in[0];
    const float* W_qkv = (const float*)d_in[1];
    const float* W_out = (const float*)d_in[2];
    const float* W_pos = (const float*)d_in[3];
    const float* u_vec = (const float*)d_in[4];
    const float* v_vec = (const float*)d_in[5];
    const float* rel   = (const float*)d_in[6];
    float* out = (float*)d_out;

    char* ws = (char*)d_ws;
    u16* x_h    = (u16*)(ws);                 // [2048][1024]
    u16* rel_h  = (u16*)(ws + 4194304);       // [2048][1024]
    u16* Wq_h   = (u16*)(ws + 8388608);       // [3072][1024]
    u16* Wpos_h = (u16*)(ws + 14680064);      // [1024][1024]
    u16* Wout_h = (u16*)(ws + 16777216);      // [1024][1024]
    u16* qk_h   = (u16*)(ws + 18874368);      // [2048][2048] (q | k)
    u16* Vt_g   = (u16*)(ws + 27262976);      // [1024][2048]
    u16* P_h    = (u16*)(ws + 31457280);      // [2048][1024]
    u16* O_h    = (u16*)(ws + 35651584);      // [2048][1024]

    prep5<<<dim3(2048), dim3(256), 0, stream>>>(
        x, x_h, 2048 * 1024 / 4,
        rel, rel_h, 2048 * 1024 / 4,
        W_qkv, Wq_h, 3072 * 1024 / 4,
        W_pos, Wpos_h, 1024 * 1024 / 4,
        W_out, Wout_h, 1024 * 1024 / 4);

    gemm_proj<<<dim3(512), dim3(256), 0, stream>>>(
        x_h, rel_h, Wq_h, Wpos_h, qk_h, Vt_g, P_h);

    attn_mfma<<<dim3(32, 16), dim3(256), 0, stream>>>(
        qk_h, Vt_g, P_h, u_vec, v_vec, O_h);

    gemm_out<<<dim3(512), dim3(256), 0, stream>>>(O_h, Wout_h, out);
}